// Round 4
// baseline (75.264 us; speedup 1.0000x reference)
//
#include <hip/hip_runtime.h>

// out[b] = SCALE * dot(x[b], sum_g wsums[g]),  SCALE = 1.5 * 0.5 = 0.75
// x: [1024, 8192] fp32 (streamed once), wsums: [32, 8192] fp32, out: [1024] fp32
//
// R7 = R4/R5/R6 resubmit (all benches failed on GPU acquisition; never measured).
// FUSED design. Previous 2-kernel split serialized a 32-CU fold kernel
// (wsum_fold) ahead of the BW-bound row-dot kernel. Now:
//   Kernel 1 (fused): grid = 8 k-chunks x 64 row-groups = 512 blocks (2/CU).
//     Phase 1: fold the block's 1024-float chunk of sum_g wsums[g] into LDS
//              (32 x 4 KiB reads; chunk = blockIdx & 7 -> all readers of a
//              chunk share an XCD under round-robin dispatch -> wsums pulled
//              from HBM exactly once, re-served from that XCD's L2).
//     Phase 2: 16 rows/block, 16 threads/row, float4 x loads, dot vs LDS,
//              16-lane shuffle reduce -> deterministic partial[row][chunk].
//   Kernel 2 (reduce): 4 blocks, out[b] = SCALE * sum_c partial[b][c].
//     Tiny (32 KiB L2-hot read) -- essentially pure launch overhead.
// Deterministic (each partial written by exactly one group; fixed-order sum).
// Desk-checked R6+R7: all index arithmetic in-bounds; d_ws use = 32 KiB (same
// as old verified design); one writer per partial; stream-ordered; no
// dispatch-order assumptions (G16); no alloc/sync in kernel_launch.
// NOTE R3 (kept): nontemporal loads on x regressed; x single-pass, plain loads.
// Floor: 33 MiB HBM ~= 5.3 us + 2 launches; harness reset (~55-60 us) dominates.

#define K_DIM 8192
#define G_DIM 32
#define SCALE 0.75f
#define NCHUNK 8
#define CHUNK (K_DIM / NCHUNK)   // 1024 floats per chunk
#define CHUNK4 (CHUNK / 4)       // 256 float4 per chunk
#define ROWS_PER 16              // rows per block
#define THREADS 256

typedef float floatx4 __attribute__((ext_vector_type(4)));

__global__ void __launch_bounds__(THREADS) fused_partial_kernel(
    const float* __restrict__ x, const float* __restrict__ wsums,
    float* __restrict__ partial) {
    const int bi     = blockIdx.x;
    const int chunk  = bi & (NCHUNK - 1);  // low bits -> XCD-affine chunk sharing
    const int rowgrp = bi >> 3;
    const int t      = threadIdx.x;

    __shared__ floatx4 w4[CHUNK4];         // 4 KiB folded w chunk

    // Phase 1: w_chunk[j] = sum_g wsums[g][chunk*1024 + j]; one float4/thread.
    {
        const floatx4* ws4 =
            reinterpret_cast<const floatx4*>(wsums) + chunk * CHUNK4 + t;
        floatx4 acc = ws4[0];
#pragma unroll
        for (int g = 1; g < G_DIM; ++g)
            acc += ws4[(size_t)g * (K_DIM / 4)];
        w4[t] = acc;
    }
    __syncthreads();

    // Phase 2: 16 threads per row; each thread 16 float4 of x vs LDS w.
    const int rlane = t & 15;
    const int row   = rowgrp * ROWS_PER + (t >> 4);
    const floatx4* xr4 = reinterpret_cast<const floatx4*>(x) +
                         (size_t)row * (K_DIM / 4) + chunk * CHUNK4 + rlane;
    float acc = 0.f;
#pragma unroll
    for (int i = 0; i < CHUNK4 / 16; ++i) {   // 16 iterations
        const floatx4 xv = xr4[i * 16];
        const floatx4 wv = w4[rlane + i * 16];
        acc += xv.x * wv.x + xv.y * wv.y + xv.z * wv.z + xv.w * wv.w;
    }

    // Reduce across the 16 lanes of this row (xor masks < 16 stay in-group).
#pragma unroll
    for (int off = 8; off > 0; off >>= 1)
        acc += __shfl_xor(acc, off, 64);

    if (rlane == 0) partial[row * NCHUNK + chunk] = acc;
}

__global__ void __launch_bounds__(256) reduce_kernel(
    const float* __restrict__ partial, float* __restrict__ out) {
    const int b = blockIdx.x * 256 + threadIdx.x;
    const floatx4* p4 = reinterpret_cast<const floatx4*>(partial) + b * 2;
    const floatx4 a = p4[0];
    const floatx4 c = p4[1];
    out[b] = (a.x + a.y + a.z + a.w + c.x + c.y + c.z + c.w) * SCALE;
}

extern "C" void kernel_launch(void* const* d_in, const int* in_sizes, int n_in,
                              void* d_out, int out_size, void* d_ws, size_t ws_size,
                              hipStream_t stream) {
    const float* x     = (const float*)d_in[0];   // [1024, 8192]
    const float* wsums = (const float*)d_in[1];   // [32, 8192]
    float* out         = (float*)d_out;           // [1024]
    float* partial     = (float*)d_ws;            // [1024][8] floats = 32 KiB

    const int n_rows = in_sizes[0] / K_DIM;       // 1024

    fused_partial_kernel<<<NCHUNK * (n_rows / ROWS_PER), THREADS, 0, stream>>>(
        x, wsums, partial);
    reduce_kernel<<<n_rows / 256, 256, 0, stream>>>(partial, out);
}